// Round 1
// baseline (469.528 us; speedup 1.0000x reference)
//
#include <hip/hip_runtime.h>

#define S_LEN 2048
#define HID 4096
#define NH 32
#define NKV 8
#define HD 128
#define KVW 1024       // NKV*HD
#define NQKV 6144      // HID + 2*KVW

typedef _Float16 f16;
typedef _Float16 f16x8 __attribute__((ext_vector_type(8)));
typedef _Float16 f16x4 __attribute__((ext_vector_type(4)));
typedef float f32x4 __attribute__((ext_vector_type(4)));

__device__ __forceinline__ void gll16(const void* g, void* lds) {
  __builtin_amdgcn_global_load_lds((const __attribute__((address_space(1))) void*)g,
                                   (__attribute__((address_space(3))) void*)lds, 16, 0, 0);
}

// ---------------- cast hidden f32 -> f16 ----------------
__global__ void k_cast(const float* __restrict__ src, f16* __restrict__ dst) {
  size_t i = ((size_t)blockIdx.x * blockDim.x + threadIdx.x) * 8;
  float4 a = *(const float4*)(src + i);
  float4 b = *(const float4*)(src + i + 4);
  f16x8 o = { (f16)a.x, (f16)a.y, (f16)a.z, (f16)a.w,
              (f16)b.x, (f16)b.y, (f16)b.z, (f16)b.w };
  *(f16x8*)(dst + i) = o;
}

// ---------------- RoPE trig table: [S][64] float4 = (cos(2i), cos(2i+1), sin(2i), sin(2i+1))
__global__ void k_trig(float4* __restrict__ trig) {
  int id = blockIdx.x * blockDim.x + threadIdx.x;
  int s = id >> 6, i = id & 63;
  int j0 = 2 * i, j1 = 2 * i + 1;
  float f0 = powf(10000.f, -(float)(j0 & 63) / 64.f);
  float f1 = powf(10000.f, -(float)(j1 & 63) / 64.f);
  float a0 = (float)s * f0, a1 = (float)s * f1;
  trig[id] = make_float4(cosf(a0), cosf(a1), sinf(a0), sinf(a1));
}

// ---------------- transpose+cast: src f32 [4096][N] -> dst f16 [N][4096]
__global__ void k_transpose(const float* __restrict__ src, f16* __restrict__ dst, int N) {
  __shared__ f16 tile[64][72];
  int nb = blockIdx.x * 64, kb = blockIdx.y * 64;
  int t = threadIdx.x;
  int kl = t >> 4, nc = (t & 15) << 2;
#pragma unroll
  for (int p = 0; p < 4; ++p) {
    int kk = kl + p * 16;
    float4 v = *(const float4*)(src + (size_t)(kb + kk) * N + nb + nc);
    f16x4 h = { (f16)v.x, (f16)v.y, (f16)v.z, (f16)v.w };
    *(f16x4*)(&tile[kk][nc]) = h;
  }
  __syncthreads();
  int nl = t >> 3, c = t & 7;
#pragma unroll
  for (int p = 0; p < 2; ++p) {
    int nn = nl + p * 32;
    f16x8 o;
#pragma unroll
    for (int i = 0; i < 8; ++i) o[i] = tile[c * 8 + i][nn];
    *(f16x8*)(dst + (size_t)(nb + nn) * HID + kb + c * 8) = o;
  }
}

// ---------------- 128x128 double-buffered f16 MFMA GEMM ----------------
// MODE 0: A=H, Bt=[wq^T;wk^T;wv^T]; epilogue: RoPE->Qr/Kr, V transposed -> Vt[d][s]
// MODE 1: A=attn_out, Bt=wo^T; epilogue: f32 store
#define BM 128
#define BN 128
#define BK 64

template<int MODE>
__global__ __launch_bounds__(256, 2) void k_gemm(
    const f16* __restrict__ A, const f16* __restrict__ Bt,
    int N, int K,
    f16* __restrict__ Qr, f16* __restrict__ Kr, f16* __restrict__ Vt,
    const float4* __restrict__ trig, float* __restrict__ Cout)
{
  __shared__ f16 As[2][BM * BK];
  __shared__ f16 Bs[2][BN * BK];
  const int tid = threadIdx.x;
  const int ln = tid & 63, w = tid >> 6;
  const int la = ln & 15, lg = ln >> 4;
  const int m0 = blockIdx.y * BM, n0 = blockIdx.x * BN;
  const int NT = K / BK;

  f32x4 acc[4][4] = {};

  size_t aoff[4], boff[4];
  int ldsc[4];
#pragma unroll
  for (int j = 0; j < 4; ++j) {
    int cch = w * 4 + j;              // 1KB chunk = 8 rows x 128B
    int r = cch * 8 + (ln >> 3);
    int gc = (ln & 7) ^ (r & 7);      // source-side XOR swizzle (LDS stays linear)
    aoff[j] = ((size_t)(m0 + r) * K) * 2 + (size_t)gc * 16;
    boff[j] = ((size_t)(n0 + r) * K) * 2 + (size_t)gc * 16;
    ldsc[j] = cch * 1024;
  }

  {
    const char* Ab = (const char*)A;
    const char* Bb = (const char*)Bt;
#pragma unroll
    for (int j = 0; j < 4; ++j) {
      gll16(Ab + aoff[j], (char*)&As[0][0] + ldsc[j]);
      gll16(Bb + boff[j], (char*)&Bs[0][0] + ldsc[j]);
    }
  }
  __syncthreads();

  const int wm = (w & 1) * 64, wn = (w >> 1) * 64;
  int arow[4], brow[4];
#pragma unroll
  for (int i = 0; i < 4; ++i) { arow[i] = wm + i * 16 + la; brow[i] = wn + i * 16 + la; }

  int cur = 0;
  for (int kt = 0; kt < NT; ++kt) {
    if (kt + 1 < NT) {
      const char* Ab = (const char*)A + (size_t)(kt + 1) * BK * 2;
      const char* Bb = (const char*)Bt + (size_t)(kt + 1) * BK * 2;
#pragma unroll
      for (int j = 0; j < 4; ++j) {
        gll16(Ab + aoff[j], (char*)&As[cur ^ 1][0] + ldsc[j]);
        gll16(Bb + boff[j], (char*)&Bs[cur ^ 1][0] + ldsc[j]);
      }
    }
    const f16* Ap = &As[cur][0];
    const f16* Bp = &Bs[cur][0];
    f16x8 af[4][2], bf[4][2];
#pragma unroll
    for (int i = 0; i < 4; ++i) {
#pragma unroll
      for (int ks = 0; ks < 2; ++ks) {
        int ca = (ks * 4 + lg) ^ (arow[i] & 7);
        int cb = (ks * 4 + lg) ^ (brow[i] & 7);
        af[i][ks] = *(const f16x8*)(Ap + arow[i] * 64 + ca * 8);
        bf[i][ks] = *(const f16x8*)(Bp + brow[i] * 64 + cb * 8);
      }
    }
#pragma unroll
    for (int mi = 0; mi < 4; ++mi)
#pragma unroll
      for (int ni = 0; ni < 4; ++ni)
#pragma unroll
        for (int ks = 0; ks < 2; ++ks)
          acc[mi][ni] = __builtin_amdgcn_mfma_f32_16x16x32_f16(af[mi][ks], bf[ni][ks], acc[mi][ni], 0, 0, 0);
    __syncthreads();
    cur ^= 1;
  }

#pragma unroll
  for (int mi = 0; mi < 4; ++mi) {
#pragma unroll
    for (int ni = 0; ni < 4; ++ni) {
      f32x4 fr = acc[mi][ni];
      int n = n0 + wn + ni * 16 + la;
      int mr = m0 + wm + mi * 16 + lg * 4;
      if (MODE == 0) {
        if (n < HID + KVW) {           // Q or K region -> RoPE
          int d = n & 127;
#pragma unroll
          for (int r = 0; r < 4; ++r) {
            float v = fr[r];
            float p = __shfl_xor(v, 1);
            float4 tc = trig[(size_t)(mr + r) * 64 + (d >> 1)];
            float cv = (d & 1) ? tc.y : tc.x;
            float sv = (d & 1) ? tc.w : tc.z;
            float o = v * cv + ((d & 1) ? p : -p) * sv;
            if (n < HID) Qr[(size_t)(mr + r) * HID + n] = (f16)o;
            else         Kr[(size_t)(mr + r) * KVW + (n - HID)] = (f16)o;
          }
        } else {                        // V region -> transposed store Vt[n][s]
          int nv = n - (HID + KVW);
          f16x4 o4 = { (f16)fr[0], (f16)fr[1], (f16)fr[2], (f16)fr[3] };
          *(f16x4*)(Vt + (size_t)nv * S_LEN + mr) = o4;
        }
      } else {
#pragma unroll
        for (int r = 0; r < 4; ++r)
          Cout[(size_t)(mr + r) * N + n] = fr[r];
      }
    }
  }
}

// ---------------- flash attention, causal, GQA ----------------
// block: 256 thr (4 waves), 128 q-rows/block (32/wave), KV tiles of 64
__global__ __launch_bounds__(256, 2) void k_attn(
    const f16* __restrict__ Qr, const f16* __restrict__ Kr, const f16* __restrict__ Vt,
    f16* __restrict__ AO)
{
  const int h = blockIdx.y, hkv = h >> 2;
  const int q0 = blockIdx.x * 128;
  __shared__ f16 Qs[128 * 128];
  __shared__ f16 Ks[64 * 128];
  __shared__ f16 Vs[128 * 64];
  __shared__ f16 Ps[4][32 * 64];
  const int tid = threadIdx.x;
  const int ln = tid & 63, w = tid >> 6;
  const int la = ln & 15, lg = ln >> 4;

  // stage Q tile [128][128] (32 x 1KB chunks, 4 rows each)
#pragma unroll
  for (int j = 0; j < 8; ++j) {
    int cb = w * 8 + j;
    int r = cb * 4 + lg;
    int gc = la ^ (r & 7);
    gll16((const char*)Qr + ((size_t)(q0 + r) * HID + h * HD) * 2 + gc * 16,
          (char*)Qs + cb * 1024);
  }

  float m_run[2][4], l_run[2][4];
  f32x4 o_acc[2][8] = {};
#pragma unroll
  for (int mi = 0; mi < 2; ++mi)
#pragma unroll
    for (int r = 0; r < 4; ++r) { m_run[mi][r] = -3.0e38f; l_run[mi][r] = 0.f; }

  f16x8 aq[2][4];
  const int NTILES = (q0 >> 6) + 2;
  const float scale = 0.08838834764831845f;  // 1/sqrt(128)

  for (int jt = 0; jt < NTILES; ++jt) {
    const int j0 = jt * 64;
#pragma unroll
    for (int j = 0; j < 4; ++j) {           // K tile [64][128]
      int cb = w * 4 + j;
      int r = cb * 4 + lg;
      int gc = la ^ (r & 7);
      gll16((const char*)Kr + ((size_t)(j0 + r) * KVW + hkv * HD) * 2 + gc * 16,
            (char*)Ks + cb * 1024);
    }
#pragma unroll
    for (int j = 0; j < 4; ++j) {           // V^T tile [128][64]
      int cb = w * 4 + j;
      int d = cb * 8 + (ln >> 3);
      int gc = (ln & 7) ^ (d & 7);
      gll16((const char*)Vt + ((size_t)(hkv * HD + d) * S_LEN + j0) * 2 + gc * 16,
            (char*)Vs + cb * 1024);
    }
    __syncthreads();
    if (jt == 0) {
#pragma unroll
      for (int mi = 0; mi < 2; ++mi)
#pragma unroll
        for (int ks = 0; ks < 4; ++ks) {
          int row = w * 32 + mi * 16 + la;
          int c = (ks * 4 + lg) ^ (row & 7);
          aq[mi][ks] = *(const f16x8*)(Qs + row * 128 + c * 8);
        }
    }
    if (j0 <= q0 + w * 32 + 31) {           // wave has unmasked work
      f32x4 sacc[2][4] = {};
#pragma unroll
      for (int nf = 0; nf < 4; ++nf)
#pragma unroll
        for (int ks = 0; ks < 4; ++ks) {
          int row = nf * 16 + la;
          int c = (ks * 4 + lg) ^ (row & 7);
          f16x8 bk = *(const f16x8*)(Ks + row * 128 + c * 8);
#pragma unroll
          for (int mi = 0; mi < 2; ++mi)
            sacc[mi][nf] = __builtin_amdgcn_mfma_f32_16x16x32_f16(aq[mi][ks], bk, sacc[mi][nf], 0, 0, 0);
        }
      const bool need_mask = (j0 + 63 > q0 + w * 32);
      float pv[2][4][4];
#pragma unroll
      for (int mi = 0; mi < 2; ++mi)
#pragma unroll
        for (int nf = 0; nf < 4; ++nf)
#pragma unroll
          for (int r = 0; r < 4; ++r) {
            float sval = sacc[mi][nf][r] * scale;
            if (need_mask) {
              int kv = j0 + nf * 16 + la;
              int q  = q0 + w * 32 + mi * 16 + lg * 4 + r;
              if (kv > q) sval = -1.0e30f;
            }
            pv[mi][nf][r] = sval;
          }
#pragma unroll
      for (int mi = 0; mi < 2; ++mi)
#pragma unroll
        for (int r = 0; r < 4; ++r) {
          float rm = fmaxf(fmaxf(pv[mi][0][r], pv[mi][1][r]), fmaxf(pv[mi][2][r], pv[mi][3][r]));
#pragma unroll
          for (int off = 1; off < 16; off <<= 1)
            rm = fmaxf(rm, __shfl_xor(rm, off));
          float mnew = fmaxf(m_run[mi][r], rm);
          float corr = __expf(m_run[mi][r] - mnew);
          m_run[mi][r] = mnew;
          float ps = 0.f;
#pragma unroll
          for (int nf = 0; nf < 4; ++nf) {
            float p = __expf(pv[mi][nf][r] - mnew);
            ps += p;
            pv[mi][nf][r] = p;
          }
#pragma unroll
          for (int off = 1; off < 16; off <<= 1)
            ps += __shfl_xor(ps, off);
          l_run[mi][r] = l_run[mi][r] * corr + ps;
#pragma unroll
          for (int ni = 0; ni < 8; ++ni)
            o_acc[mi][ni][r] *= corr;
        }
#pragma unroll
      for (int mi = 0; mi < 2; ++mi)
#pragma unroll
        for (int nf = 0; nf < 4; ++nf)
#pragma unroll
          for (int r = 0; r < 4; ++r) {
            int row = mi * 16 + lg * 4 + r;
            int col = nf * 16 + la;
            int cc = (col >> 3) ^ (row & 7);
            Ps[w][row * 64 + cc * 8 + (col & 7)] = (f16)pv[mi][nf][r];
          }
      asm volatile("s_waitcnt lgkmcnt(0)" ::: "memory");
      f16x8 pa[2][2];
#pragma unroll
      for (int mi = 0; mi < 2; ++mi)
#pragma unroll
        for (int ks = 0; ks < 2; ++ks) {
          int row = mi * 16 + la;
          int c = (ks * 4 + lg) ^ (row & 7);
          pa[mi][ks] = *(const f16x8*)(&Ps[w][0] + row * 64 + c * 8);
        }
#pragma unroll
      for (int ni = 0; ni < 8; ++ni)
#pragma unroll
        for (int ks = 0; ks < 2; ++ks) {
          int d = ni * 16 + la;
          int c = (ks * 4 + lg) ^ (d & 7);
          f16x8 bv = *(const f16x8*)(Vs + d * 64 + c * 8);
#pragma unroll
          for (int mi = 0; mi < 2; ++mi)
            o_acc[mi][ni] = __builtin_amdgcn_mfma_f32_16x16x32_f16(pa[mi][ks], bv, o_acc[mi][ni], 0, 0, 0);
        }
    }
    __syncthreads();
  }

#pragma unroll
  for (int mi = 0; mi < 2; ++mi)
#pragma unroll
    for (int r = 0; r < 4; ++r) {
      float inv = 1.f / l_run[mi][r];
#pragma unroll
      for (int ni = 0; ni < 8; ++ni) {
        size_t row = (size_t)q0 + w * 32 + mi * 16 + lg * 4 + r;
        AO[row * HID + h * HD + ni * 16 + la] = (f16)(o_acc[mi][ni][r] * inv);
      }
    }
}

extern "C" void kernel_launch(void* const* d_in, const int* in_sizes, int n_in,
                              void* d_out, int out_size, void* d_ws, size_t ws_size,
                              hipStream_t stream) {
  const float* hs = (const float*)d_in[0];
  // d_in[1] = attention_mask (pure causal; handled analytically)
  const float* wq = (const float*)d_in[2];
  const float* wk = (const float*)d_in[3];
  const float* wv = (const float*)d_in[4];
  const float* wo = (const float*)d_in[5];
  float* out = (float*)d_out;

  char* ws = (char*)d_ws;
  size_t off = 0;
  auto alloc = [&](size_t b) { char* p = ws + off; off += (b + 255) & ~(size_t)255; return p; };
  f16* Hh   = (f16*)alloc((size_t)S_LEN * HID * 2);
  f16* Wt   = (f16*)alloc((size_t)NQKV * HID * 2);
  f16* Wot  = (f16*)alloc((size_t)HID * HID * 2);
  float4* trig = (float4*)alloc((size_t)S_LEN * 64 * sizeof(float4));
  f16* Qrp  = (f16*)alloc((size_t)S_LEN * HID * 2);
  f16* Krp  = (f16*)alloc((size_t)S_LEN * KVW * 2);
  f16* Vtp  = (f16*)alloc((size_t)KVW * S_LEN * 2);
  f16* AO   = (f16*)alloc((size_t)S_LEN * HID * 2);

  k_cast<<<(S_LEN * HID) / (256 * 8), 256, 0, stream>>>(hs, Hh);
  k_trig<<<(S_LEN * 64) / 256, 256, 0, stream>>>(trig);
  k_transpose<<<dim3(HID / 64, HID / 64), 256, 0, stream>>>(wq, Wt, HID);
  k_transpose<<<dim3(KVW / 64, HID / 64), 256, 0, stream>>>(wk, Wt + (size_t)HID * HID, KVW);
  k_transpose<<<dim3(KVW / 64, HID / 64), 256, 0, stream>>>(wv, Wt + (size_t)(HID + KVW) * HID, KVW);
  k_transpose<<<dim3(HID / 64, HID / 64), 256, 0, stream>>>(wo, Wot, HID);
  k_gemm<0><<<dim3(NQKV / BN, S_LEN / BM), 256, 0, stream>>>(Hh, Wt, NQKV, HID, Qrp, Krp, Vtp, trig, nullptr);
  k_attn<<<dim3(S_LEN / 128, NH), 256, 0, stream>>>(Qrp, Krp, Vtp, AO);
  k_gemm<1><<<dim3(HID / BN, S_LEN / BM), 256, 0, stream>>>(AO, Wot, HID, HID, nullptr, nullptr, nullptr, nullptr, out);
}

// Round 2
// 437.603 us; speedup vs baseline: 1.0730x; 1.0730x over previous
//
#include <hip/hip_runtime.h>

#define S_LEN 2048
#define HID 4096
#define NH 32
#define NKV 8
#define HD 128
#define KVW 1024       // NKV*HD
#define NQKV 6144      // HID + 2*KVW

typedef _Float16 f16;
typedef _Float16 f16x8 __attribute__((ext_vector_type(8)));
typedef _Float16 f16x4 __attribute__((ext_vector_type(4)));
typedef float f32x4 __attribute__((ext_vector_type(4)));

__device__ __forceinline__ void gll16(const void* g, void* lds) {
  __builtin_amdgcn_global_load_lds((const __attribute__((address_space(1))) void*)g,
                                   (__attribute__((address_space(3))) void*)lds, 16, 0, 0);
}

// ---------------- cast hidden f32 -> f16 ----------------
__global__ void k_cast(const float* __restrict__ src, f16* __restrict__ dst) {
  size_t i = ((size_t)blockIdx.x * blockDim.x + threadIdx.x) * 8;
  float4 a = *(const float4*)(src + i);
  float4 b = *(const float4*)(src + i + 4);
  f16x8 o = { (f16)a.x, (f16)a.y, (f16)a.z, (f16)a.w,
              (f16)b.x, (f16)b.y, (f16)b.z, (f16)b.w };
  *(f16x8*)(dst + i) = o;
}

// ---------------- RoPE trig table: [S][64] float4 = (cos(2i), cos(2i+1), sin(2i), sin(2i+1))
__global__ void k_trig(float4* __restrict__ trig) {
  int id = blockIdx.x * blockDim.x + threadIdx.x;
  int s = id >> 6, i = id & 63;
  int j0 = 2 * i, j1 = 2 * i + 1;
  float f0 = powf(10000.f, -(float)(j0 & 63) / 64.f);
  float f1 = powf(10000.f, -(float)(j1 & 63) / 64.f);
  float a0 = (float)s * f0, a1 = (float)s * f1;
  trig[id] = make_float4(cosf(a0), cosf(a1), sinf(a0), sinf(a1));
}

// ---------------- transpose+cast: src f32 [4096][N] -> dst f16 [N][4096]
__global__ void k_transpose(const float* __restrict__ src, f16* __restrict__ dst, int N) {
  __shared__ f16 tile[64][72];
  int nb = blockIdx.x * 64, kb = blockIdx.y * 64;
  int t = threadIdx.x;
  int kl = t >> 4, nc = (t & 15) << 2;
#pragma unroll
  for (int p = 0; p < 4; ++p) {
    int kk = kl + p * 16;
    float4 v = *(const float4*)(src + (size_t)(kb + kk) * N + nb + nc);
    f16x4 h = { (f16)v.x, (f16)v.y, (f16)v.z, (f16)v.w };
    *(f16x4*)(&tile[kk][nc]) = h;
  }
  __syncthreads();
  int nl = t >> 3, c = t & 7;
#pragma unroll
  for (int p = 0; p < 2; ++p) {
    int nn = nl + p * 32;
    f16x8 o;
#pragma unroll
    for (int i = 0; i < 8; ++i) o[i] = tile[c * 8 + i][nn];
    *(f16x8*)(dst + (size_t)(nb + nn) * HID + kb + c * 8) = o;
  }
}

// ---------------- 128x128 single-buffered f16 MFMA GEMM (m97 structure) ----------------
// MODE 0: A=H, Bt=[wq^T;wk^T;wv^T]; epilogue: RoPE->Qr/Kr, V transposed -> Vt[d][s]
// MODE 1: A=attn_out, Bt=wo^T; epilogue: f32 store
#define BM 128
#define BN 128
#define BK 64

template<int MODE>
__global__ __launch_bounds__(256, 4) void k_gemm(
    const f16* __restrict__ A, const f16* __restrict__ Bt,
    int N, int K,
    f16* __restrict__ Qr, f16* __restrict__ Kr, f16* __restrict__ Vt,
    const float4* __restrict__ trig, float* __restrict__ Cout)
{
  __shared__ f16 As[BM * BK];   // 16 KB
  __shared__ f16 Bs[BN * BK];   // 16 KB
  const int tid = threadIdx.x;
  const int ln = tid & 63, w = tid >> 6;
  const int la = ln & 15, lg = ln >> 4;
  const int m0 = blockIdx.y * BM, n0 = blockIdx.x * BN;
  const int NT = K / BK;

  f32x4 acc[4][4] = {};

  size_t aoff[4], boff[4];
  int ldsc[4];
#pragma unroll
  for (int j = 0; j < 4; ++j) {
    int cch = w * 4 + j;              // 1KB chunk = 8 rows x 128B
    int r = cch * 8 + (ln >> 3);
    int gc = (ln & 7) ^ (r & 7);      // source-side XOR swizzle (LDS stays linear)
    aoff[j] = ((size_t)(m0 + r) * K) * 2 + (size_t)gc * 16;
    boff[j] = ((size_t)(n0 + r) * K) * 2 + (size_t)gc * 16;
    ldsc[j] = cch * 1024;
  }

  const int wm = (w & 1) * 64, wn = (w >> 1) * 64;
  int arow[4], brow[4];
#pragma unroll
  for (int i = 0; i < 4; ++i) { arow[i] = wm + i * 16 + la; brow[i] = wn + i * 16 + la; }

  for (int kt = 0; kt < NT; ++kt) {
    const char* Ab = (const char*)A + (size_t)kt * BK * 2;
    const char* Bb = (const char*)Bt + (size_t)kt * BK * 2;
#pragma unroll
    for (int j = 0; j < 4; ++j) {
      gll16(Ab + aoff[j], (char*)&As[0] + ldsc[j]);
      gll16(Bb + boff[j], (char*)&Bs[0] + ldsc[j]);
    }
    __syncthreads();   // drains vmcnt: staged tile visible to all waves
    f16x8 af[4][2], bf[4][2];
#pragma unroll
    for (int i = 0; i < 4; ++i) {
#pragma unroll
      for (int ks = 0; ks < 2; ++ks) {
        int ca = (ks * 4 + lg) ^ (arow[i] & 7);
        int cb = (ks * 4 + lg) ^ (brow[i] & 7);
        af[i][ks] = *(const f16x8*)(As + arow[i] * 64 + ca * 8);
        bf[i][ks] = *(const f16x8*)(Bs + brow[i] * 64 + cb * 8);
      }
    }
#pragma unroll
    for (int mi = 0; mi < 4; ++mi)
#pragma unroll
      for (int ni = 0; ni < 4; ++ni)
#pragma unroll
        for (int ks = 0; ks < 2; ++ks)
          acc[mi][ni] = __builtin_amdgcn_mfma_f32_16x16x32_f16(af[mi][ks], bf[ni][ks], acc[mi][ni], 0, 0, 0);
    __syncthreads();   // all waves done reading before next stage overwrites
  }

#pragma unroll
  for (int mi = 0; mi < 4; ++mi) {
#pragma unroll
    for (int ni = 0; ni < 4; ++ni) {
      f32x4 fr = acc[mi][ni];
      int n = n0 + wn + ni * 16 + la;
      int mr = m0 + wm + mi * 16 + lg * 4;
      if (MODE == 0) {
        if (n < HID + KVW) {           // Q or K region -> RoPE
          int d = n & 127;
#pragma unroll
          for (int r = 0; r < 4; ++r) {
            float v = fr[r];
            float p = __shfl_xor(v, 1);
            float4 tc = trig[(size_t)(mr + r) * 64 + (d >> 1)];
            float cv = (d & 1) ? tc.y : tc.x;
            float sv = (d & 1) ? tc.w : tc.z;
            float o = v * cv + ((d & 1) ? p : -p) * sv;
            if (n < HID) Qr[(size_t)(mr + r) * HID + n] = (f16)o;
            else         Kr[(size_t)(mr + r) * KVW + (n - HID)] = (f16)o;
          }
        } else {                        // V region -> transposed store Vt[n][s]
          int nv = n - (HID + KVW);
          f16x4 o4 = { (f16)fr[0], (f16)fr[1], (f16)fr[2], (f16)fr[3] };
          *(f16x4*)(Vt + (size_t)nv * S_LEN + mr) = o4;
        }
      } else {
#pragma unroll
        for (int r = 0; r < 4; ++r)
          Cout[(size_t)(mr + r) * N + n] = fr[r];
      }
    }
  }
}

// ---------------- flash attention, causal, GQA ----------------
// block: 256 thr (4 waves), 128 q-rows/block (32/wave), KV tiles of 64
__global__ __launch_bounds__(256, 2) void k_attn(
    const f16* __restrict__ Qr, const f16* __restrict__ Kr, const f16* __restrict__ Vt,
    f16* __restrict__ AO)
{
  const int h = blockIdx.y, hkv = h >> 2;
  const int q0 = blockIdx.x * 128;
  __shared__ f16 Qs[128 * 128];
  __shared__ f16 Ks[64 * 128];
  __shared__ f16 Vs[128 * 64];
  __shared__ f16 Ps[4][32 * 64];
  const int tid = threadIdx.x;
  const int ln = tid & 63, w = tid >> 6;
  const int la = ln & 15, lg = ln >> 4;

  // stage Q tile [128][128] (32 x 1KB chunks, 4 rows each)
#pragma unroll
  for (int j = 0; j < 8; ++j) {
    int cb = w * 8 + j;
    int r = cb * 4 + lg;
    int gc = la ^ (r & 7);
    gll16((const char*)Qr + ((size_t)(q0 + r) * HID + h * HD) * 2 + gc * 16,
          (char*)Qs + cb * 1024);
  }

  float m_run[2][4], l_run[2][4];
  f32x4 o_acc[2][8] = {};
#pragma unroll
  for (int mi = 0; mi < 2; ++mi)
#pragma unroll
    for (int r = 0; r < 4; ++r) { m_run[mi][r] = -3.0e38f; l_run[mi][r] = 0.f; }

  f16x8 aq[2][4];
  const int NTILES = (q0 >> 6) + 2;
  const float scale = 0.08838834764831845f;  // 1/sqrt(128)

  for (int jt = 0; jt < NTILES; ++jt) {
    const int j0 = jt * 64;
#pragma unroll
    for (int j = 0; j < 4; ++j) {           // K tile [64][128]
      int cb = w * 4 + j;
      int r = cb * 4 + lg;
      int gc = la ^ (r & 7);
      gll16((const char*)Kr + ((size_t)(j0 + r) * KVW + hkv * HD) * 2 + gc * 16,
            (char*)Ks + cb * 1024);
    }
#pragma unroll
    for (int j = 0; j < 4; ++j) {           // V^T tile [128][64]
      int cb = w * 4 + j;
      int d = cb * 8 + (ln >> 3);
      int gc = (ln & 7) ^ (d & 7);
      gll16((const char*)Vt + ((size_t)(hkv * HD + d) * S_LEN + j0) * 2 + gc * 16,
            (char*)Vs + cb * 1024);
    }
    __syncthreads();
    if (jt == 0) {
#pragma unroll
      for (int mi = 0; mi < 2; ++mi)
#pragma unroll
        for (int ks = 0; ks < 4; ++ks) {
          int row = w * 32 + mi * 16 + la;
          int c = (ks * 4 + lg) ^ (row & 7);
          aq[mi][ks] = *(const f16x8*)(Qs + row * 128 + c * 8);
        }
    }
    if (j0 <= q0 + w * 32 + 31) {           // wave has unmasked work
      f32x4 sacc[2][4] = {};
#pragma unroll
      for (int nf = 0; nf < 4; ++nf)
#pragma unroll
        for (int ks = 0; ks < 4; ++ks) {
          int row = nf * 16 + la;
          int c = (ks * 4 + lg) ^ (row & 7);
          f16x8 bk = *(const f16x8*)(Ks + row * 128 + c * 8);
#pragma unroll
          for (int mi = 0; mi < 2; ++mi)
            sacc[mi][nf] = __builtin_amdgcn_mfma_f32_16x16x32_f16(aq[mi][ks], bk, sacc[mi][nf], 0, 0, 0);
        }
      const bool need_mask = (j0 + 63 > q0 + w * 32);
      float pv[2][4][4];
#pragma unroll
      for (int mi = 0; mi < 2; ++mi)
#pragma unroll
        for (int nf = 0; nf < 4; ++nf)
#pragma unroll
          for (int r = 0; r < 4; ++r) {
            float sval = sacc[mi][nf][r] * scale;
            if (need_mask) {
              int kv = j0 + nf * 16 + la;
              int q  = q0 + w * 32 + mi * 16 + lg * 4 + r;
              if (kv > q) sval = -1.0e30f;
            }
            pv[mi][nf][r] = sval;
          }
#pragma unroll
      for (int mi = 0; mi < 2; ++mi)
#pragma unroll
        for (int r = 0; r < 4; ++r) {
          float rm = fmaxf(fmaxf(pv[mi][0][r], pv[mi][1][r]), fmaxf(pv[mi][2][r], pv[mi][3][r]));
#pragma unroll
          for (int off = 1; off < 16; off <<= 1)
            rm = fmaxf(rm, __shfl_xor(rm, off));
          float mnew = fmaxf(m_run[mi][r], rm);
          float corr = __expf(m_run[mi][r] - mnew);
          m_run[mi][r] = mnew;
          float ps = 0.f;
#pragma unroll
          for (int nf = 0; nf < 4; ++nf) {
            float p = __expf(pv[mi][nf][r] - mnew);
            ps += p;
            pv[mi][nf][r] = p;
          }
#pragma unroll
          for (int off = 1; off < 16; off <<= 1)
            ps += __shfl_xor(ps, off);
          l_run[mi][r] = l_run[mi][r] * corr + ps;
#pragma unroll
          for (int ni = 0; ni < 8; ++ni)
            o_acc[mi][ni][r] *= corr;
        }
#pragma unroll
      for (int mi = 0; mi < 2; ++mi)
#pragma unroll
        for (int nf = 0; nf < 4; ++nf)
#pragma unroll
          for (int r = 0; r < 4; ++r) {
            int row = mi * 16 + lg * 4 + r;
            int col = nf * 16 + la;
            int cc = (col >> 3) ^ (row & 7);
            Ps[w][row * 64 + cc * 8 + (col & 7)] = (f16)pv[mi][nf][r];
          }
      asm volatile("s_waitcnt lgkmcnt(0)" ::: "memory");
      f16x8 pa[2][2];
#pragma unroll
      for (int mi = 0; mi < 2; ++mi)
#pragma unroll
        for (int ks = 0; ks < 2; ++ks) {
          int row = mi * 16 + la;
          int c = (ks * 4 + lg) ^ (row & 7);
          pa[mi][ks] = *(const f16x8*)(&Ps[w][0] + row * 64 + c * 8);
        }
#pragma unroll
      for (int ni = 0; ni < 8; ++ni)
#pragma unroll
        for (int ks = 0; ks < 2; ++ks) {
          int d = ni * 16 + la;
          int c = (ks * 4 + lg) ^ (d & 7);
          f16x8 bv = *(const f16x8*)(Vs + d * 64 + c * 8);
#pragma unroll
          for (int mi = 0; mi < 2; ++mi)
            o_acc[mi][ni] = __builtin_amdgcn_mfma_f32_16x16x32_f16(pa[mi][ks], bv, o_acc[mi][ni], 0, 0, 0);
        }
    }
    __syncthreads();
  }

#pragma unroll
  for (int mi = 0; mi < 2; ++mi)
#pragma unroll
    for (int r = 0; r < 4; ++r) {
      float inv = 1.f / l_run[mi][r];
#pragma unroll
      for (int ni = 0; ni < 8; ++ni) {
        size_t row = (size_t)q0 + w * 32 + mi * 16 + lg * 4 + r;
        AO[row * HID + h * HD + ni * 16 + la] = (f16)(o_acc[mi][ni][r] * inv);
      }
    }
}

extern "C" void kernel_launch(void* const* d_in, const int* in_sizes, int n_in,
                              void* d_out, int out_size, void* d_ws, size_t ws_size,
                              hipStream_t stream) {
  const float* hs = (const float*)d_in[0];
  // d_in[1] = attention_mask (pure causal; handled analytically)
  const float* wq = (const float*)d_in[2];
  const float* wk = (const float*)d_in[3];
  const float* wv = (const float*)d_in[4];
  const float* wo = (const float*)d_in[5];
  float* out = (float*)d_out;

  char* ws = (char*)d_ws;
  size_t off = 0;
  auto alloc = [&](size_t b) { char* p = ws + off; off += (b + 255) & ~(size_t)255; return p; };
  f16* Hh   = (f16*)alloc((size_t)S_LEN * HID * 2);
  f16* Wt   = (f16*)alloc((size_t)NQKV * HID * 2);
  f16* Wot  = (f16*)alloc((size_t)HID * HID * 2);
  float4* trig = (float4*)alloc((size_t)S_LEN * 64 * sizeof(float4));
  f16* Qrp  = (f16*)alloc((size_t)S_LEN * HID * 2);
  f16* Krp  = (f16*)alloc((size_t)S_LEN * KVW * 2);
  f16* Vtp  = (f16*)alloc((size_t)KVW * S_LEN * 2);
  f16* AO   = (f16*)alloc((size_t)S_LEN * HID * 2);

  k_cast<<<(S_LEN * HID) / (256 * 8), 256, 0, stream>>>(hs, Hh);
  k_trig<<<(S_LEN * 64) / 256, 256, 0, stream>>>(trig);
  k_transpose<<<dim3(HID / 64, HID / 64), 256, 0, stream>>>(wq, Wt, HID);
  k_transpose<<<dim3(KVW / 64, HID / 64), 256, 0, stream>>>(wk, Wt + (size_t)HID * HID, KVW);
  k_transpose<<<dim3(KVW / 64, HID / 64), 256, 0, stream>>>(wv, Wt + (size_t)(HID + KVW) * HID, KVW);
  k_transpose<<<dim3(HID / 64, HID / 64), 256, 0, stream>>>(wo, Wot, HID);
  k_gemm<0><<<dim3(NQKV / BN, S_LEN / BM), 256, 0, stream>>>(Hh, Wt, NQKV, HID, Qrp, Krp, Vtp, trig, nullptr);
  k_attn<<<dim3(S_LEN / 128, NH), 256, 0, stream>>>(Qrp, Krp, Vtp, AO);
  k_gemm<1><<<dim3(HID / BN, S_LEN / BM), 256, 0, stream>>>(AO, Wot, HID, HID, nullptr, nullptr, nullptr, nullptr, out);
}

// Round 3
// 356.541 us; speedup vs baseline: 1.3169x; 1.2274x over previous
//
#include <hip/hip_runtime.h>

#define S_LEN 2048
#define HID 4096
#define NH 32
#define NKV 8
#define HD 128
#define KVW 1024       // NKV*HD
#define NQKV 6144      // HID + 2*KVW

typedef _Float16 f16;
typedef _Float16 f16x8 __attribute__((ext_vector_type(8)));
typedef _Float16 f16x4 __attribute__((ext_vector_type(4)));
typedef float f32x4 __attribute__((ext_vector_type(4)));
typedef float f32x16 __attribute__((ext_vector_type(16)));
typedef unsigned int u32;
typedef u32 u32x4 __attribute__((ext_vector_type(4)));

__device__ __forceinline__ void gll16(const void* g, void* lds) {
  __builtin_amdgcn_global_load_lds((const __attribute__((address_space(1))) void*)g,
                                   (__attribute__((address_space(3))) void*)lds, 16, 0, 0);
}

// ---------------- cast hidden f32 -> f16 ----------------
__global__ void k_cast(const float* __restrict__ src, f16* __restrict__ dst) {
  size_t i = ((size_t)blockIdx.x * blockDim.x + threadIdx.x) * 8;
  float4 a = *(const float4*)(src + i);
  float4 b = *(const float4*)(src + i + 4);
  f16x8 o = { (f16)a.x, (f16)a.y, (f16)a.z, (f16)a.w,
              (f16)b.x, (f16)b.y, (f16)b.z, (f16)b.w };
  *(f16x8*)(dst + i) = o;
}

// ---------------- RoPE trig table: [S][64] float4 = (cos(2i), cos(2i+1), sin(2i), sin(2i+1))
__global__ void k_trig(float4* __restrict__ trig) {
  int id = blockIdx.x * blockDim.x + threadIdx.x;
  int s = id >> 6, i = id & 63;
  int j0 = 2 * i, j1 = 2 * i + 1;
  float f0 = powf(10000.f, -(float)(j0 & 63) / 64.f);
  float f1 = powf(10000.f, -(float)(j1 & 63) / 64.f);
  float a0 = (float)s * f0, a1 = (float)s * f1;
  trig[id] = make_float4(cosf(a0), cosf(a1), sinf(a0), sinf(a1));
}

// ---------------- transpose+cast: src f32 [4096][N] -> dst f16 [N][4096]
__global__ void k_transpose(const float* __restrict__ src, f16* __restrict__ dst, int N) {
  __shared__ f16 tile[64][72];
  int nb = blockIdx.x * 64, kb = blockIdx.y * 64;
  int t = threadIdx.x;
  int kl = t >> 4, nc = (t & 15) << 2;
#pragma unroll
  for (int p = 0; p < 4; ++p) {
    int kk = kl + p * 16;
    float4 v = *(const float4*)(src + (size_t)(kb + kk) * N + nb + nc);
    f16x4 h = { (f16)v.x, (f16)v.y, (f16)v.z, (f16)v.w };
    *(f16x4*)(&tile[kk][nc]) = h;
  }
  __syncthreads();
  int nl = t >> 3, c = t & 7;
#pragma unroll
  for (int p = 0; p < 2; ++p) {
    int nn = nl + p * 32;
    f16x8 o;
#pragma unroll
    for (int i = 0; i < 8; ++i) o[i] = tile[c * 8 + i][nn];
    *(f16x8*)(dst + (size_t)(nb + nn) * HID + kb + c * 8) = o;
  }
}

// ---------------- 128x128 single-buffered f16 MFMA GEMM (m97 structure) ----------------
#define BM 128
#define BN 128
#define BK 64

template<int MODE>
__global__ __launch_bounds__(256, 4) void k_gemm(
    const f16* __restrict__ A, const f16* __restrict__ Bt,
    int N, int K,
    f16* __restrict__ Qr, f16* __restrict__ Kr, f16* __restrict__ Vt,
    const float4* __restrict__ trig, float* __restrict__ Cout)
{
  __shared__ f16 As[BM * BK];   // 16 KB
  __shared__ f16 Bs[BN * BK];   // 16 KB
  const int tid = threadIdx.x;
  const int ln = tid & 63, w = tid >> 6;
  const int la = ln & 15, lg = ln >> 4;
  const int m0 = blockIdx.y * BM, n0 = blockIdx.x * BN;
  const int NT = K / BK;

  f32x4 acc[4][4] = {};

  size_t aoff[4], boff[4];
  int ldsc[4];
#pragma unroll
  for (int j = 0; j < 4; ++j) {
    int cch = w * 4 + j;              // 1KB chunk = 8 rows x 128B
    int r = cch * 8 + (ln >> 3);
    int gc = (ln & 7) ^ (r & 7);      // source-side XOR swizzle (LDS stays linear)
    aoff[j] = ((size_t)(m0 + r) * K) * 2 + (size_t)gc * 16;
    boff[j] = ((size_t)(n0 + r) * K) * 2 + (size_t)gc * 16;
    ldsc[j] = cch * 1024;
  }

  const int wm = (w & 1) * 64, wn = (w >> 1) * 64;
  int arow[4], brow[4];
#pragma unroll
  for (int i = 0; i < 4; ++i) { arow[i] = wm + i * 16 + la; brow[i] = wn + i * 16 + la; }

  for (int kt = 0; kt < NT; ++kt) {
    const char* Ab = (const char*)A + (size_t)kt * BK * 2;
    const char* Bb = (const char*)Bt + (size_t)kt * BK * 2;
#pragma unroll
    for (int j = 0; j < 4; ++j) {
      gll16(Ab + aoff[j], (char*)&As[0] + ldsc[j]);
      gll16(Bb + boff[j], (char*)&Bs[0] + ldsc[j]);
    }
    __syncthreads();
    f16x8 af[4][2], bf[4][2];
#pragma unroll
    for (int i = 0; i < 4; ++i) {
#pragma unroll
      for (int ks = 0; ks < 2; ++ks) {
        int ca = (ks * 4 + lg) ^ (arow[i] & 7);
        int cb = (ks * 4 + lg) ^ (brow[i] & 7);
        af[i][ks] = *(const f16x8*)(As + arow[i] * 64 + ca * 8);
        bf[i][ks] = *(const f16x8*)(Bs + brow[i] * 64 + cb * 8);
      }
    }
#pragma unroll
    for (int mi = 0; mi < 4; ++mi)
#pragma unroll
      for (int ni = 0; ni < 4; ++ni)
#pragma unroll
        for (int ks = 0; ks < 2; ++ks)
          acc[mi][ni] = __builtin_amdgcn_mfma_f32_16x16x32_f16(af[mi][ks], bf[ni][ks], acc[mi][ni], 0, 0, 0);
    __syncthreads();
  }

#pragma unroll
  for (int mi = 0; mi < 4; ++mi) {
#pragma unroll
    for (int ni = 0; ni < 4; ++ni) {
      f32x4 fr = acc[mi][ni];
      int n = n0 + wn + ni * 16 + la;
      int mr = m0 + wm + mi * 16 + lg * 4;
      if (MODE == 0) {
        if (n < HID + KVW) {           // Q or K region -> RoPE
          int d = n & 127;
#pragma unroll
          for (int r = 0; r < 4; ++r) {
            float v = fr[r];
            float p = __shfl_xor(v, 1);
            float4 tc = trig[(size_t)(mr + r) * 64 + (d >> 1)];
            float cv = (d & 1) ? tc.y : tc.x;
            float sv = (d & 1) ? tc.w : tc.z;
            float o = v * cv + ((d & 1) ? p : -p) * sv;
            if (n < HID) Qr[(size_t)(mr + r) * HID + n] = (f16)o;
            else         Kr[(size_t)(mr + r) * KVW + (n - HID)] = (f16)o;
          }
        } else {                        // V region -> transposed store Vt[n][s]
          int nv = n - (HID + KVW);
          f16x4 o4 = { (f16)fr[0], (f16)fr[1], (f16)fr[2], (f16)fr[3] };
          *(f16x4*)(Vt + (size_t)nv * S_LEN + mr) = o4;
        }
      } else {
#pragma unroll
        for (int r = 0; r < 4; ++r)
          Cout[(size_t)(mr + r) * N + n] = fr[r];
      }
    }
  }
}

// ---------------- flash attention, causal, GQA — swapped-QK^T 32x32 MFMA ----------------
// 4 waves x 32 q-rows = 128-row chunk per block. Grid 512: bid k and k+256 map to
// (same head, chunks c and 15-c) so round-robin dispatch pairs complementary work per CU.
#define KBYTES (64 * 128 * 2)   // 16KB K tile [64 kv][128 hd]
#define VBYTES (128 * 64 * 2)   // 16KB V tile [128 d][64 kv]

__global__ __launch_bounds__(256, 2) void k_attn(
    const f16* __restrict__ Qr, const f16* __restrict__ Kr, const f16* __restrict__ Vt,
    f16* __restrict__ AO)
{
  int bid = blockIdx.x;
  int h, c;
  if (bid < 256) { h = bid >> 3; c = bid & 7; }
  else           { int t = bid - 256; h = t >> 3; c = 15 - (t & 7); }
  const int hkv = h >> 2;
  const int q0c = c * 128;
  const int NT = 2 * c + 2;

  __shared__ char KV[2][KBYTES + VBYTES];   // 64KB total (double-buffered K+V)

  const int tid = threadIdx.x;
  const int ln = tid & 63, w = tid >> 6;
  const int q = ln & 31;            // q col within wave tile (C col = lane&31)
  const int hi = ln >> 5;
  const int qg = q0c + w * 32 + q;  // this lane's global q row

  // ---- staging address precompute (4 K-chunks + 4 V-chunks of 1KB per wave) ----
  size_t ksrc[4], vsrc[4];
  int kdo[4], vdo[4];
#pragma unroll
  for (int j = 0; j < 4; ++j) {
    int kc = w * 4 + j;                    // K chunk: 4 rows x 256B
    int kr = kc * 4 + (ln >> 4);           // kv row 0..63
    ksrc[j] = ((size_t)kr * KVW + hkv * HD) * 2 + (size_t)(((ln & 15) ^ (kr & 7)) * 16);
    kdo[j] = kc * 1024;
    int vc = w * 4 + j;                    // V chunk: 8 rows x 128B
    int d = vc * 8 + (ln >> 3);            // d row 0..127
    vsrc[j] = ((size_t)(hkv * HD + d) * S_LEN) * 2 + (size_t)(((ln & 7) ^ (d & 7)) * 16);
    vdo[j] = KBYTES + vc * 1024;
  }

  // ---- Q fragments from global (B-frag: col q = lane&31, k = hi*8+j) ----
  f16x8 qf[8];
  {
    const f16* qrow = Qr + (size_t)qg * HID + h * HD + hi * 8;
#pragma unroll
    for (int ks = 0; ks < 8; ++ks) qf[ks] = *(const f16x8*)(qrow + ks * 16);
  }

  f32x16 ot[4] = {};
  float m2 = -3.0e38f, l = 0.f;
  const float K2 = 0.12753256471f;  // log2(e)/sqrt(128)

  int buf = 0;
  // prologue: stage tile 0 into buf 0
#pragma unroll
  for (int j = 0; j < 4; ++j) {
    gll16((const char*)Kr + ksrc[j], &KV[0][kdo[j]]);
    gll16((const char*)Vt + vsrc[j], &KV[0][vdo[j]]);
  }

  for (int jt = 0; jt < NT; ++jt) {
    __syncthreads();                       // tile jt staged & visible
    if (jt + 1 < NT) {                     // prefetch jt+1 into other buffer
      size_t ko = (size_t)(jt + 1) * 64 * KVW * 2;
      size_t vo = (size_t)(jt + 1) * 64 * 2;
#pragma unroll
      for (int j = 0; j < 4; ++j) {
        gll16((const char*)Kr + ksrc[j] + ko, &KV[buf ^ 1][kdo[j]]);
        gll16((const char*)Vt + vsrc[j] + vo, &KV[buf ^ 1][vdo[j]]);
      }
    }
    const int j0 = jt * 64;
    if (j0 <= q0c + w * 32 + 31) {         // wave has unmasked rows this tile
      const f16* Kb = (const f16*)&KV[buf][0];
      const f16* Vb = (const f16*)&KV[buf][KBYTES];
      // ---- QK^T (swapped): S^T[kv][q], two 32-kv chunks ----
      f32x16 s0 = {}, s1 = {};
#pragma unroll
      for (int ks = 0; ks < 8; ++ks) {
        int cc = ((ks * 2 + hi) ^ (q & 7)) * 8;
        f16x8 k0 = *(const f16x8*)(Kb + q * 128 + cc);
        f16x8 k1 = *(const f16x8*)(Kb + (q + 32) * 128 + cc);
        s0 = __builtin_amdgcn_mfma_f32_32x32x16_f16(k0, qf[ks], s0, 0, 0, 0);
        s1 = __builtin_amdgcn_mfma_f32_32x32x16_f16(k1, qf[ks], s1, 0, 0, 0);
      }
      // ---- mask + row max (row = q, lane-local + one cross-half swap) ----
      const bool nm = (j0 + 63 > q0c + w * 32);
      float p0[16], p1[16];
      float mx = -3.0e38f;
#pragma unroll
      for (int r = 0; r < 16; ++r) {
        float a = s0[r], b = s1[r];
        if (nm) {
          int kvb = j0 + (r & 3) + 8 * (r >> 2) + 4 * hi;
          if (kvb > qg) a = -3.0e38f;
          if (kvb + 32 > qg) b = -3.0e38f;
        }
        p0[r] = a; p1[r] = b;
        mx = fmaxf(mx, fmaxf(a, b));
      }
      mx = fmaxf(mx, __shfl_xor(mx, 32));
      float m2c = mx * K2;
      int defer = (m2c <= m2 + 11.0f);     // T13 defer-max (exp2 domain)
      if (!__all(defer)) {
        float m2n = fmaxf(m2, m2c);
        float corr = exp2f(m2 - m2n);
        m2 = m2n; l *= corr;
#pragma unroll
        for (int t = 0; t < 4; ++t)
#pragma unroll
          for (int r = 0; r < 16; ++r) ot[t][r] *= corr;
      }
      // ---- exp + row sum ----
      float sum = 0.f;
#pragma unroll
      for (int r = 0; r < 16; ++r) {
        p0[r] = exp2f(__builtin_fmaf(p0[r], K2, -m2));
        p1[r] = exp2f(__builtin_fmaf(p1[r], K2, -m2));
        sum += p0[r] + p1[r];
      }
      l += sum + __shfl_xor(sum, 32);
      // ---- pack P -> f16, redistribute to B-frag layout (8 shfl + 8 sel per chunk) ----
      u32 pw0[8], pw1[8];
#pragma unroll
      for (int t = 0; t < 8; ++t) {
        pw0[t] = __builtin_bit_cast(u32, __builtin_amdgcn_cvt_pkrtz(p0[2 * t], p0[2 * t + 1]));
        pw1[t] = __builtin_bit_cast(u32, __builtin_amdgcn_cvt_pkrtz(p1[2 * t], p1[2 * t + 1]));
      }
      f16x8 pf[4];
#pragma unroll
      for (int ch = 0; ch < 2; ++ch) {
        const u32* pw = ch ? pw1 : pw0;
        u32 sx[8];
#pragma unroll
        for (int t = 0; t < 8; ++t) sx[t] = (u32)__shfl_xor((int)pw[t], 32);
        u32x4 fa = { hi ? sx[2] : pw[0], hi ? sx[3] : pw[1],
                     hi ? pw[2] : sx[0], hi ? pw[3] : sx[1] };
        u32x4 fb = { hi ? sx[6] : pw[4], hi ? sx[7] : pw[5],
                     hi ? pw[6] : sx[4], hi ? pw[7] : sx[5] };
        pf[ch * 2 + 0] = __builtin_bit_cast(f16x8, fa);
        pf[ch * 2 + 1] = __builtin_bit_cast(f16x8, fb);
      }
      // ---- PV: O^T[d][q] += V^T-frag x P^T-frag ----
#pragma unroll
      for (int dt = 0; dt < 4; ++dt) {
        int d = dt * 32 + q;
#pragma unroll
        for (int f = 0; f < 4; ++f) {
          f16x8 vf = *(const f16x8*)(Vb + d * 64 + (((f * 2 + hi) ^ (q & 7)) * 8));
          ot[dt] = __builtin_amdgcn_mfma_f32_32x32x16_f16(vf, pf[f], ot[dt], 0, 0, 0);
        }
      }
    }
    buf ^= 1;
  }

  // ---- epilogue: O^T/l -> LDS transpose (per-wave scratch) -> coalesced AO ----
  __syncthreads();
  char* scr = &KV[0][0] + w * 8192;   // 32 rows x 256B per wave
  float inv = 1.f / l;
#pragma unroll
  for (int dt = 0; dt < 4; ++dt) {
#pragma unroll
    for (int rg = 0; rg < 4; ++rg) {
      u32 wa = __builtin_bit_cast(u32, __builtin_amdgcn_cvt_pkrtz(ot[dt][rg * 4 + 0] * inv, ot[dt][rg * 4 + 1] * inv));
      u32 wb = __builtin_bit_cast(u32, __builtin_amdgcn_cvt_pkrtz(ot[dt][rg * 4 + 2] * inv, ot[dt][rg * 4 + 3] * inv));
      int byte = q * 256 + (((dt * 4 + rg) ^ (q & 7)) * 16) + hi * 8;
      u32* p = (u32*)(scr + byte);
      p[0] = wa; p[1] = wb;
    }
  }
  asm volatile("s_waitcnt lgkmcnt(0)" ::: "memory");
#pragma unroll
  for (int ps = 0; ps < 8; ++ps) {
    int qr = ps * 4 + (ln >> 4);
    int ck = (ln & 15) ^ (qr & 7);
    f16x8 v = *(const f16x8*)(scr + qr * 256 + ck * 16);
    *(f16x8*)(AO + (size_t)(q0c + w * 32 + qr) * HID + h * HD + (ln & 15) * 8) = v;
  }
}

extern "C" void kernel_launch(void* const* d_in, const int* in_sizes, int n_in,
                              void* d_out, int out_size, void* d_ws, size_t ws_size,
                              hipStream_t stream) {
  const float* hs = (const float*)d_in[0];
  // d_in[1] = attention_mask (pure causal; handled analytically)
  const float* wq = (const float*)d_in[2];
  const float* wk = (const float*)d_in[3];
  const float* wv = (const float*)d_in[4];
  const float* wo = (const float*)d_in[5];
  float* out = (float*)d_out;

  char* ws = (char*)d_ws;
  size_t off = 0;
  auto alloc = [&](size_t b) { char* p = ws + off; off += (b + 255) & ~(size_t)255; return p; };
  f16* Hh   = (f16*)alloc((size_t)S_LEN * HID * 2);
  f16* Wt   = (f16*)alloc((size_t)NQKV * HID * 2);
  f16* Wot  = (f16*)alloc((size_t)HID * HID * 2);
  float4* trig = (float4*)alloc((size_t)S_LEN * 64 * sizeof(float4));
  f16* Qrp  = (f16*)alloc((size_t)S_LEN * HID * 2);
  f16* Krp  = (f16*)alloc((size_t)S_LEN * KVW * 2);
  f16* Vtp  = (f16*)alloc((size_t)KVW * S_LEN * 2);
  f16* AO   = (f16*)alloc((size_t)S_LEN * HID * 2);

  k_cast<<<(S_LEN * HID) / (256 * 8), 256, 0, stream>>>(hs, Hh);
  k_trig<<<(S_LEN * 64) / 256, 256, 0, stream>>>(trig);
  k_transpose<<<dim3(HID / 64, HID / 64), 256, 0, stream>>>(wq, Wt, HID);
  k_transpose<<<dim3(KVW / 64, HID / 64), 256, 0, stream>>>(wk, Wt + (size_t)HID * HID, KVW);
  k_transpose<<<dim3(KVW / 64, HID / 64), 256, 0, stream>>>(wv, Wt + (size_t)(HID + KVW) * HID, KVW);
  k_transpose<<<dim3(HID / 64, HID / 64), 256, 0, stream>>>(wo, Wot, HID);
  k_gemm<0><<<dim3(NQKV / BN, S_LEN / BM), 256, 0, stream>>>(Hh, Wt, NQKV, HID, Qrp, Krp, Vtp, trig, nullptr);
  k_attn<<<dim3(512), 256, 0, stream>>>(Qrp, Krp, Vtp, AO);
  k_gemm<1><<<dim3(HID / BN, S_LEN / BM), 256, 0, stream>>>(AO, Wot, HID, HID, nullptr, nullptr, nullptr, nullptr, out);
}